// Round 15
// baseline (922.786 us; speedup 1.0000x reference)
//
#include <hip/hip_runtime.h>
#include <hip/hip_fp16.h>
#include <math.h>

#define N_NODES 50000
#define E_ORIG  800000
#define E_TOT   850000   // + self loops
#define SNB     49       // scan blocks: 49 * 1024 >= N_NODES
#define BPG     782      // gather node-blocks per slice: 782 * 64 >= N_NODES
#define CAP     1280     // LDS edge-window: mean block edge-count 1088, +5.8 sigma
#define WSCALE  0.00390625f   // 2^-8: keeps half2(w) < fp16 max up to logit ~16.6

typedef __attribute__((ext_vector_type(8))) short    short8;
typedef __attribute__((ext_vector_type(8))) _Float16 half8;
typedef __attribute__((ext_vector_type(4))) float    f32x4;

__device__ __forceinline__ short f2h(float f) {             // fp32 -> fp16 RNE
    _Float16 h = (_Float16)f;
    return __builtin_bit_cast(short, h);
}

// ---------------- fp16 MFMA GEMM + fused logits epilogue ----------------
// C_t[blk][m][32] slice-major. LOGMODE 1 (layers 1/2): wave's 64 cols = 2 heads ->
// in-wave shfl reduction. LOGMODE 2 (layer 3): one head spans all 128 cols = 2 waves ->
// per-wave partials + cross-wave LDS reduce. Logits from fp32 acc (pre-quantization).
template<bool AF32, int LOGMODE>
__global__ __launch_bounds__(256) void gemm_f16(const void* __restrict__ Av,
                                                const short* __restrict__ Wt,   // W^T [N][K] fp16
                                                short* __restrict__ C,          // [N/32][N_NODES][32]
                                                int M, int N, int K,
                                                const float* __restrict__ a_src,
                                                const float* __restrict__ a_dst,
                                                float* __restrict__ al_s,
                                                float* __restrict__ al_d)
{
    __shared__ short sA[128][40];
    __shared__ short sB[128][40];
    const int t    = threadIdx.x;
    const int wave = t >> 6, lane = t & 63;
    const int quad = lane >> 4, mrow = lane & 15;
    const int m0 = blockIdx.y * 128, n0 = blockIdx.x * 128;
    const int wm = (wave & 1) * 64, wn = (wave >> 1) * 64;

    f32x4 acc[4][4] = {};

    const int ra = t >> 2, ka = (t & 3) << 3;
    const int nb = t >> 1, kb = (t & 1) << 4;

    for (int k0 = 0; k0 < K; k0 += 32) {
#pragma unroll
        for (int rr = 0; rr < 2; ++rr) {
            int row = ra + rr * 64;
            int gm = m0 + row;
            if (AF32) {
                const float* Af = (const float*)Av;
                float4 v0 = make_float4(0.f, 0.f, 0.f, 0.f), v1 = v0;
                if (gm < M) {
                    const float* src = Af + (size_t)gm * K + k0 + ka;
                    v0 = *(const float4*)src;
                    v1 = *(const float4*)(src + 4);
                }
                sA[row][ka + 0] = f2h(v0.x); sA[row][ka + 1] = f2h(v0.y);
                sA[row][ka + 2] = f2h(v0.z); sA[row][ka + 3] = f2h(v0.w);
                sA[row][ka + 4] = f2h(v1.x); sA[row][ka + 5] = f2h(v1.y);
                sA[row][ka + 6] = f2h(v1.z); sA[row][ka + 7] = f2h(v1.w);
            } else {
                const short* Ab = (const short*)Av;
                int4 v = {0, 0, 0, 0};
                if (gm < M) v = *(const int4*)(Ab + (size_t)gm * K + k0 + ka);
                *(int4*)&sA[row][ka] = v;
            }
        }
        {
            const int4* src = (const int4*)(Wt + (size_t)(n0 + nb) * K + k0 + kb);
            *(int4*)&sB[nb][kb]     = src[0];
            *(int4*)&sB[nb][kb + 8] = src[1];
        }
        __syncthreads();
        short8 af[4], bfr[4];
#pragma unroll
        for (int mi = 0; mi < 4; ++mi)
            af[mi] = *(const short8*)&sA[wm + mi * 16 + mrow][quad * 8];
#pragma unroll
        for (int ni = 0; ni < 4; ++ni)
            bfr[ni] = *(const short8*)&sB[wn + ni * 16 + mrow][quad * 8];
#pragma unroll
        for (int mi = 0; mi < 4; ++mi)
#pragma unroll
            for (int ni = 0; ni < 4; ++ni)
                acc[mi][ni] = __builtin_amdgcn_mfma_f32_16x16x32_f16(
                    __builtin_bit_cast(half8, af[mi]),
                    __builtin_bit_cast(half8, bfr[ni]), acc[mi][ni], 0, 0, 0);
        __syncthreads();
    }
    // C/D layout: col = lane&15, row = quad*4 + reg; write slice-major
#pragma unroll
    for (int mi = 0; mi < 4; ++mi) {
#pragma unroll
        for (int ni = 0; ni < 4; ++ni) {
            int gn = n0 + wn + ni * 16 + mrow;
            size_t sbase = ((size_t)(gn >> 5) * N_NODES) * 32 + (gn & 31);
            int gmb = m0 + wm + mi * 16 + quad * 4;
#pragma unroll
            for (int r = 0; r < 4; ++r) {
                int gm = gmb + r;
                if (gm < M) C[sbase + (size_t)gm * 32] = f2h(acc[mi][ni][r]);
            }
        }
    }
    if constexpr (LOGMODE == 1) {
        float as_c[4], ad_c[4];
#pragma unroll
        for (int ni = 0; ni < 4; ++ni) {
            int gn = n0 + wn + ni * 16 + mrow;
            as_c[ni] = a_src[gn];
            ad_c[ni] = a_dst[gn];
        }
        int h0 = (n0 + wn) >> 5;          // wave's 2 heads: h0, h0+1
#pragma unroll
        for (int mi = 0; mi < 4; ++mi) {
#pragma unroll
            for (int r = 0; r < 4; ++r) {
                float s0 = acc[mi][0][r] * as_c[0] + acc[mi][1][r] * as_c[1];
                float s1 = acc[mi][2][r] * as_c[2] + acc[mi][3][r] * as_c[3];
                float d0 = acc[mi][0][r] * ad_c[0] + acc[mi][1][r] * ad_c[1];
                float d1 = acc[mi][2][r] * ad_c[2] + acc[mi][3][r] * ad_c[3];
#pragma unroll
                for (int off = 1; off < 16; off <<= 1) {
                    s0 += __shfl_xor(s0, off, 16);
                    s1 += __shfl_xor(s1, off, 16);
                    d0 += __shfl_xor(d0, off, 16);
                    d1 += __shfl_xor(d1, off, 16);
                }
                if (mrow == 0) {
                    int gm = m0 + wm + mi * 16 + quad * 4 + r;
                    if (gm < M) {
                        al_s[(size_t)h0 * N_NODES + gm]       = s0;
                        al_s[(size_t)(h0 + 1) * N_NODES + gm] = s1;
                        al_d[(size_t)h0 * N_NODES + gm]       = d0;
                        al_d[(size_t)(h0 + 1) * N_NODES + gm] = d1;
                    }
                }
            }
        }
    }
    if constexpr (LOGMODE == 2) {   // single head over 128 cols: cross-wave reduce
        __shared__ float s_red[4][2][128];
        float as_c[4], ad_c[4];
#pragma unroll
        for (int ni = 0; ni < 4; ++ni) {
            int gn = wn + ni * 16 + mrow;     // n0 == 0 (grid.x == 1)
            as_c[ni] = a_src[gn];
            ad_c[ni] = a_dst[gn];
        }
#pragma unroll
        for (int mi = 0; mi < 4; ++mi) {
#pragma unroll
            for (int r = 0; r < 4; ++r) {
                float s = acc[mi][0][r] * as_c[0] + acc[mi][1][r] * as_c[1]
                        + acc[mi][2][r] * as_c[2] + acc[mi][3][r] * as_c[3];
                float d = acc[mi][0][r] * ad_c[0] + acc[mi][1][r] * ad_c[1]
                        + acc[mi][2][r] * ad_c[2] + acc[mi][3][r] * ad_c[3];
#pragma unroll
                for (int off = 1; off < 16; off <<= 1) {
                    s += __shfl_xor(s, off, 16);
                    d += __shfl_xor(d, off, 16);
                }
                if (mrow == 0) {
                    int lrow = wm + mi * 16 + quad * 4 + r;
                    s_red[wave][0][lrow] = s;
                    s_red[wave][1][lrow] = d;
                }
            }
        }
        __syncthreads();
        if (t < 128) {
            int gm = m0 + t;
            if (gm < M) {
                int ws = t >> 6;              // rows 0-63: waves 0&2; 64-127: waves 1&3
                al_s[gm] = s_red[ws][0][t] + s_red[ws + 2][0][t];
                al_d[gm] = s_red[ws][1][t] + s_red[ws + 2][1][t];
            }
        }
    }
}

// ---------------- W^T casts, one launch ----------------
__global__ void wtcast_all(const float* __restrict__ W1, const float* __restrict__ W2,
                           const float* __restrict__ W3, short* __restrict__ wt)
{
    int i = blockIdx.x * blockDim.x + threadIdx.x;
    if (i < 32768) {                       // W1: K=128, N=256
        int n = i / 128, k = i % 128;
        wt[i] = f2h(W1[(size_t)k * 256 + n]);
    } else if (i < 98304) {                // W2: K=256, N=256
        int j = i - 32768;
        int n = j / 256, k = j % 256;
        wt[i] = f2h(W2[(size_t)k * 256 + n]);
    } else if (i < 131072) {               // W3: K=256, N=128
        int j = i - 98304;
        int n = j / 256, k = j % 256;
        wt[i] = f2h(W3[(size_t)k * 128 + n]);
    }
}

// ---------------- CSR build ----------------
__global__ void deg_kernel(const int* __restrict__ ei, int* __restrict__ deg)
{
    int e = blockIdx.x * blockDim.x + threadIdx.x;
    if (e >= E_TOT) return;
    int d = (e < E_ORIG) ? ei[E_ORIG + e] : e - E_ORIG;
    atomicAdd(&deg[d], 1);
}

__global__ __launch_bounds__(256) void scan_p1(const int* __restrict__ deg, int* __restrict__ bsum)
{
    __shared__ int wsum[4];
    int t = threadIdx.x;
    int base = blockIdx.x * 1024 + t * 4;
    int s = 0;
    if (base + 3 < N_NODES) {
        int4 v = *(const int4*)(deg + base);
        s = v.x + v.y + v.z + v.w;
    } else if (base < N_NODES) {
        for (int j = 0; j < 4 && base + j < N_NODES; ++j) s += deg[base + j];
    }
#pragma unroll
    for (int d = 32; d; d >>= 1) s += __shfl_down(s, d);
    if ((t & 63) == 0) wsum[t >> 6] = s;
    __syncthreads();
    if (t == 0) bsum[blockIdx.x] = wsum[0] + wsum[1] + wsum[2] + wsum[3];
}

// p2 merged in: each block redundantly prefixes the 49 block sums (cheap).
__global__ __launch_bounds__(256) void scan_p3(const int* __restrict__ deg,
                                               const int* __restrict__ bsum,
                                               int* __restrict__ row_ptr,
                                               int* __restrict__ cursor)
{
    __shared__ int tsum[256];
    int t = threadIdx.x;
    int b = blockIdx.x;
    int bpre = 0;
    for (int i = 0; i < b; ++i) bpre += bsum[i];
    int base = b * 1024 + t * 4;
    int d0 = 0, d1 = 0, d2 = 0, d3 = 0;
    if (base + 3 < N_NODES) {
        int4 v = *(const int4*)(deg + base);
        d0 = v.x; d1 = v.y; d2 = v.z; d3 = v.w;
    } else if (base < N_NODES) {
        d0 = deg[base];
        if (base + 1 < N_NODES) d1 = deg[base + 1];
        if (base + 2 < N_NODES) d2 = deg[base + 2];
    }
    int s = d0 + d1 + d2 + d3;
    tsum[t] = s;
    __syncthreads();
    for (int off = 1; off < 256; off <<= 1) {
        int u = (t >= off) ? tsum[t - off] : 0;
        __syncthreads();
        tsum[t] += u;
        __syncthreads();
    }
    int run = bpre + tsum[t] - s;
    if (base < N_NODES)     { row_ptr[base]     = run; cursor[base]     = run; run += d0; }
    if (base + 1 < N_NODES) { row_ptr[base + 1] = run; cursor[base + 1] = run; run += d1; }
    if (base + 2 < N_NODES) { row_ptr[base + 2] = run; cursor[base + 2] = run; run += d2; }
    if (base + 3 < N_NODES) { row_ptr[base + 3] = run; cursor[base + 3] = run; }
    if (b == SNB - 1 && t == 255) row_ptr[N_NODES] = bpre + tsum[255];
}

// packed CSR fill: colp = src | ((dst & 63) << 16). src < 65536; gather blocks are
// 64-aligned node ranges so dst-n0 == dst & 63.
__global__ void fill_kernel(const int* __restrict__ ei, int* __restrict__ cursor,
                            int* __restrict__ colp)
{
    int e = blockIdx.x * blockDim.x + threadIdx.x;
    if (e >= E_TOT) return;
    int s, d;
    if (e < E_ORIG) { s = ei[e]; d = ei[E_ORIG + e]; } else { s = d = e - E_ORIG; }
    int pos = atomicAdd(&cursor[d], 1);
    colp[pos] = s | ((d & 63) << 16);
}

// ---------------- slice-blocked gather: XCD-pinned, LDS-staged, 2-deep load pipeline ----
// Double-buffered 4-edge batches: batch b+1's ds_reads + h-loads issue BEFORE batch b's
// consume, keeping 8 h-loads in flight (partial vmcnt waits) - attacks the diagnosed
// latency wall (R11-R14: 4 inner-loop variants all ~94-99 us).
template<int HC, int H, bool BN, bool OUTH>
__global__ __launch_bounds__(256) void gat_gather_lds(const int* __restrict__ row_ptr,
                                                      const int* __restrict__ colp,
                                                      const short* __restrict__ ht,
                                                      const float* __restrict__ al_s,
                                                      const float* __restrict__ al_d,
                                                      const float* __restrict__ bias,
                                                      const float* __restrict__ gamma,
                                                      const float* __restrict__ beta,
                                                      const float* __restrict__ mean,
                                                      const float* __restrict__ var,
                                                      void* __restrict__ outp)
{
    constexpr int NBLK = HC / 32;
    __shared__ int2  s_cw[CAP];          // {src, half2(w*2^-8)}
    __shared__ float s_ald[64];          // al_d for the block's 64 dst nodes
    int blk  = blockIdx.x % NBLK;        // slice id == XCD id (mod 8)
    int nb   = blockIdx.x / NBLK;
    int t    = threadIdx.x;
    int n    = nb * 64 + (t >> 2);
    int lane = t & 3;
    int head = (blk * H) / NBLK;
    int c_loc = lane * 8;
    const short* hb  = ht + (size_t)blk * N_NODES * 32 + c_loc;
    const float* als = al_s + (size_t)head * N_NODES;

    int n0 = nb * 64;
    int n1 = n0 + 64; if (n1 > N_NODES) n1 = N_NODES;
    if (t < 64 && n0 + t < N_NODES) s_ald[t] = al_d[(size_t)head * N_NODES + n0 + t];
    int eb = row_ptr[n0], ee = row_ptr[n1];

    int mybeg = 0, myend = 0;
    if (n < N_NODES) { mybeg = row_ptr[n]; myend = row_ptr[n + 1]; }
    __syncthreads();

    __half2 acc0 = __float2half2_rn(0.f), acc1 = acc0, acc2 = acc0, acc3 = acc0;
    __half2 den2 = __float2half2_rn(0.f);
#define CONSUME(cwj, hvj) { \
        __half2 w2 = __builtin_bit_cast(__half2, (cwj).y); \
        den2 = __hadd2(den2, w2); \
        acc0 = __hfma2(w2, __builtin_bit_cast(__half2, (hvj).x), acc0); \
        acc1 = __hfma2(w2, __builtin_bit_cast(__half2, (hvj).y), acc1); \
        acc2 = __hfma2(w2, __builtin_bit_cast(__half2, (hvj).z), acc2); \
        acc3 = __hfma2(w2, __builtin_bit_cast(__half2, (hvj).w), acc3); }

    for (int w0 = eb; w0 < ee; w0 += CAP) {
        int w1 = w0 + CAP; if (w1 > ee) w1 = ee;
        // ---- cooperative staging (coalesced; one thread per edge) ----
        for (int i = w0 + t; i < w1; i += 256) {
            int cp = colp[i];
            int c = cp & 0xFFFF;
            float v = als[c] + s_ald[cp >> 16];
            v = v > 0.f ? v : 0.2f * v;
            __half2 w2 = __float2half2_rn(__expf(v) * WSCALE);
            s_cw[i - w0] = make_int2(c, __builtin_bit_cast(int, w2));
        }
        __syncthreads();
        // ---- per-node accumulate with 2-deep pipeline ----
        int lo = mybeg > w0 ? mybeg : w0;
        int hi = myend < w1 ? myend : w1;
        int e = lo;
        int nfull = (hi - lo) >> 2;
        if (nfull > 0) {
            int2 cw[2][4]; int4 hv[2][4];
#pragma unroll
            for (int j = 0; j < 4; ++j) {
                cw[0][j] = s_cw[lo - w0 + j];
                hv[0][j] = *(const int4*)(hb + (size_t)cw[0][j].x * 32);
            }
            int cur = 0;
            for (int b = 1; b < nfull; ++b) {
                int base = lo + b * 4 - w0;
                int nxt = cur ^ 1;
#pragma unroll
                for (int j = 0; j < 4; ++j) {
                    cw[nxt][j] = s_cw[base + j];
                    hv[nxt][j] = *(const int4*)(hb + (size_t)cw[nxt][j].x * 32);
                }
#pragma unroll
                for (int j = 0; j < 4; ++j) CONSUME(cw[cur][j], hv[cur][j]);
                cur = nxt;
            }
#pragma unroll
            for (int j = 0; j < 4; ++j) CONSUME(cw[cur][j], hv[cur][j]);
            e = lo + nfull * 4;
        }
        for (; e < hi; ++e) {
            int2 cwr = s_cw[e - w0];
            int4 hr = *(const int4*)(hb + (size_t)cwr.x * 32);
            CONSUME(cwr, hr);
        }
        __syncthreads();
    }
#undef CONSUME
    if (n >= N_NODES) return;
    float inv = 1.0f / __low2float(den2);    // 2^-8 scale cancels (acc & den both carry it)
    float2 f0 = __half22float2(acc0), f1 = __half22float2(acc1);
    float2 f2 = __half22float2(acc2), f3 = __half22float2(acc3);
    float r[8] = { f0.x * inv, f0.y * inv, f1.x * inv, f1.y * inv,
                   f2.x * inv, f2.y * inv, f3.x * inv, f3.y * inv };
    int cb = blk * 32 + c_loc;
#pragma unroll
    for (int j = 0; j < 8; ++j) {
        int c = cb + j;
        float v = r[j] + bias[c];
        if (BN) {
            v = (v - mean[c]) * rsqrtf(var[c] + 1e-5f) * gamma[c] + beta[c];
            v = v > 0.f ? v : expm1f(v);   // ELU
        }
        r[j] = v;
    }
    if (OUTH) {
        short8 o;
#pragma unroll
        for (int j = 0; j < 8; ++j) o[j] = f2h(r[j]);
        *(short8*)((short*)outp + (size_t)n * HC + cb) = o;
    } else {
        float* op = (float*)outp + (size_t)n * HC + cb;
        *(float4*)op       = make_float4(r[0], r[1], r[2], r[3]);
        *(float4*)(op + 4) = make_float4(r[4], r[5], r[6], r[7]);
    }
}

extern "C" void kernel_launch(void* const* d_in, const int* in_sizes, int n_in,
                              void* d_out, int out_size, void* d_ws, size_t ws_size,
                              hipStream_t stream)
{
    const float* x   = (const float*)d_in[0];
    const int*   ei  = (const int*)d_in[1];
    const float* W1  = (const float*)d_in[2];
    const float* as1 = (const float*)d_in[3];
    const float* ad1 = (const float*)d_in[4];
    const float* b1  = (const float*)d_in[5];
    const float* g1  = (const float*)d_in[6];
    const float* be1 = (const float*)d_in[7];
    const float* mn1 = (const float*)d_in[8];
    const float* vr1 = (const float*)d_in[9];
    const float* W2  = (const float*)d_in[10];
    const float* as2 = (const float*)d_in[11];
    const float* ad2 = (const float*)d_in[12];
    const float* b2  = (const float*)d_in[13];
    const float* g2  = (const float*)d_in[14];
    const float* be2 = (const float*)d_in[15];
    const float* mn2 = (const float*)d_in[16];
    const float* vr2 = (const float*)d_in[17];
    const float* W3  = (const float*)d_in[18];
    const float* as3 = (const float*)d_in[19];
    const float* ad3 = (const float*)d_in[20];
    const float* b3  = (const float*)d_in[21];

    char* p = (char*)d_ws;
    short* hbuf    = (short*)p; p += (size_t)N_NODES * 256 * 2;     // 25.6 MB (slice-major h, fp16)
    short* obuf    = (short*)p; p += (size_t)N_NODES * 256 * 2;     // 25.6 MB (row-major layer out, fp16)
    short* wtbuf   = (short*)p; p += (size_t)131072 * 2;            // 256 KB (wt1|wt2|wt3)
    float* als     = (float*)p; p += (size_t)N_NODES * 8 * 4;       // head-major [h][n]
    float* ald     = (float*)p; p += (size_t)N_NODES * 8 * 4;
    int*   row_ptr = (int*)p;   p += (size_t)(N_NODES + 1) * 4;
    int*   colp    = (int*)p;   p += (size_t)E_TOT * 4;
    int*   deg     = (int*)p;   p += (size_t)N_NODES * 4;
    int*   cursor  = (int*)p;   p += (size_t)N_NODES * 4;
    int*   bsum    = (int*)p;   p += 64 * 4;

    short* wt1 = wtbuf;           // [256][128]
    short* wt2 = wtbuf + 32768;   // [256][256]
    short* wt3 = wtbuf + 98304;   // [128][256]

    float* out = (float*)d_out;

    // ----- CSR build + weight casts -----
    hipMemsetAsync(deg, 0, (size_t)N_NODES * 4, stream);
    deg_kernel<<<(E_TOT + 255) / 256, 256, 0, stream>>>(ei, deg);
    scan_p1<<<SNB, 256, 0, stream>>>(deg, bsum);
    scan_p3<<<SNB, 256, 0, stream>>>(deg, bsum, row_ptr, cursor);
    fill_kernel<<<(E_TOT + 255) / 256, 256, 0, stream>>>(ei, cursor, colp);
    wtcast_all<<<(131072 + 255) / 256, 256, 0, stream>>>(W1, W2, W3, wtbuf);

    // ----- layer 1: GAT(128 -> 8x32) + BN + ELU (x cast + logits fused into GEMM) -----
    gemm_f16<true, 1><<<dim3(2, (N_NODES + 127) / 128), 256, 0, stream>>>(
        x, wt1, hbuf, N_NODES, 256, 128, as1, ad1, als, ald);
    gat_gather_lds<256, 8, true, true><<<BPG * 8, 256, 0, stream>>>(
        row_ptr, colp, hbuf, als, ald, b1, g1, be1, mn1, vr1, obuf);

    // ----- layer 2: GAT(256 -> 8x32) + BN + ELU (logits fused into GEMM) -----
    gemm_f16<false, 1><<<dim3(2, (N_NODES + 127) / 128), 256, 0, stream>>>(
        obuf, wt2, hbuf, N_NODES, 256, 256, as2, ad2, als, ald);
    gat_gather_lds<256, 8, true, true><<<BPG * 8, 256, 0, stream>>>(
        row_ptr, colp, hbuf, als, ald, b2, g2, be2, mn2, vr2, obuf);

    // ----- layer 3: GAT(256 -> 1x128), heads=1 (logits fused via cross-wave reduce) -----
    gemm_f16<false, 2><<<dim3(1, (N_NODES + 127) / 128), 256, 0, stream>>>(
        obuf, wt3, hbuf, N_NODES, 128, 256, as3, ad3, als, ald);
    gat_gather_lds<128, 1, false, false><<<BPG * 4, 256, 0, stream>>>(
        row_ptr, colp, hbuf, als, ald, b3, nullptr, nullptr, nullptr, nullptr, out);
}

// Round 16
// 504.301 us; speedup vs baseline: 1.8298x; 1.8298x over previous
//
#include <hip/hip_runtime.h>
#include <hip/hip_fp16.h>
#include <math.h>

#define N_NODES 50000
#define E_ORIG  800000
#define E_TOT   850000   // + self loops
#define SNB     49       // scan blocks: 49 * 1024 >= N_NODES
#define BPG     782      // gather node-blocks per slice: 782 * 64 >= N_NODES
#define CAP     1280     // LDS edge-window: mean block edge-count 1088, +5.8 sigma
#define WSCALE  0.00390625f   // 2^-8: keeps half2(w) < fp16 max up to logit ~16.6

typedef __attribute__((ext_vector_type(8))) short    short8;
typedef __attribute__((ext_vector_type(8))) _Float16 half8;
typedef __attribute__((ext_vector_type(4))) float    f32x4;

__device__ __forceinline__ short f2h(float f) {             // fp32 -> fp16 RNE
    _Float16 h = (_Float16)f;
    return __builtin_bit_cast(short, h);
}

// ---------------- fp16 MFMA GEMM + fused logits epilogue ----------------
// C_t[blk][m][32] slice-major. LOGMODE 1 (layers 1/2): wave's 64 cols = 2 heads ->
// in-wave shfl reduction. LOGMODE 2 (layer 3): one head spans 128 cols = 2 waves ->
// per-wave partials + cross-wave LDS reduce. Logits from fp32 acc (pre-quantization).
template<bool AF32, int LOGMODE>
__global__ __launch_bounds__(256) void gemm_f16(const void* __restrict__ Av,
                                                const short* __restrict__ Wt,   // W^T [N][K] fp16
                                                short* __restrict__ C,          // [N/32][N_NODES][32]
                                                int M, int N, int K,
                                                const float* __restrict__ a_src,
                                                const float* __restrict__ a_dst,
                                                float* __restrict__ al_s,
                                                float* __restrict__ al_d)
{
    __shared__ short sA[128][40];
    __shared__ short sB[128][40];
    const int t    = threadIdx.x;
    const int wave = t >> 6, lane = t & 63;
    const int quad = lane >> 4, mrow = lane & 15;
    const int m0 = blockIdx.y * 128, n0 = blockIdx.x * 128;
    const int wm = (wave & 1) * 64, wn = (wave >> 1) * 64;

    f32x4 acc[4][4] = {};

    const int ra = t >> 2, ka = (t & 3) << 3;
    const int nb = t >> 1, kb = (t & 1) << 4;

    for (int k0 = 0; k0 < K; k0 += 32) {
#pragma unroll
        for (int rr = 0; rr < 2; ++rr) {
            int row = ra + rr * 64;
            int gm = m0 + row;
            if (AF32) {
                const float* Af = (const float*)Av;
                float4 v0 = make_float4(0.f, 0.f, 0.f, 0.f), v1 = v0;
                if (gm < M) {
                    const float* src = Af + (size_t)gm * K + k0 + ka;
                    v0 = *(const float4*)src;
                    v1 = *(const float4*)(src + 4);
                }
                sA[row][ka + 0] = f2h(v0.x); sA[row][ka + 1] = f2h(v0.y);
                sA[row][ka + 2] = f2h(v0.z); sA[row][ka + 3] = f2h(v0.w);
                sA[row][ka + 4] = f2h(v1.x); sA[row][ka + 5] = f2h(v1.y);
                sA[row][ka + 6] = f2h(v1.z); sA[row][ka + 7] = f2h(v1.w);
            } else {
                const short* Ab = (const short*)Av;
                int4 v = {0, 0, 0, 0};
                if (gm < M) v = *(const int4*)(Ab + (size_t)gm * K + k0 + ka);
                *(int4*)&sA[row][ka] = v;
            }
        }
        {
            const int4* src = (const int4*)(Wt + (size_t)(n0 + nb) * K + k0 + kb);
            *(int4*)&sB[nb][kb]     = src[0];
            *(int4*)&sB[nb][kb + 8] = src[1];
        }
        __syncthreads();
        short8 af[4], bfr[4];
#pragma unroll
        for (int mi = 0; mi < 4; ++mi)
            af[mi] = *(const short8*)&sA[wm + mi * 16 + mrow][quad * 8];
#pragma unroll
        for (int ni = 0; ni < 4; ++ni)
            bfr[ni] = *(const short8*)&sB[wn + ni * 16 + mrow][quad * 8];
#pragma unroll
        for (int mi = 0; mi < 4; ++mi)
#pragma unroll
            for (int ni = 0; ni < 4; ++ni)
                acc[mi][ni] = __builtin_amdgcn_mfma_f32_16x16x32_f16(
                    __builtin_bit_cast(half8, af[mi]),
                    __builtin_bit_cast(half8, bfr[ni]), acc[mi][ni], 0, 0, 0);
        __syncthreads();
    }
    // C/D layout: col = lane&15, row = quad*4 + reg; write slice-major
#pragma unroll
    for (int mi = 0; mi < 4; ++mi) {
#pragma unroll
        for (int ni = 0; ni < 4; ++ni) {
            int gn = n0 + wn + ni * 16 + mrow;
            size_t sbase = ((size_t)(gn >> 5) * N_NODES) * 32 + (gn & 31);
            int gmb = m0 + wm + mi * 16 + quad * 4;
#pragma unroll
            for (int r = 0; r < 4; ++r) {
                int gm = gmb + r;
                if (gm < M) C[sbase + (size_t)gm * 32] = f2h(acc[mi][ni][r]);
            }
        }
    }
    if constexpr (LOGMODE == 1) {
        float as_c[4], ad_c[4];
#pragma unroll
        for (int ni = 0; ni < 4; ++ni) {
            int gn = n0 + wn + ni * 16 + mrow;
            as_c[ni] = a_src[gn];
            ad_c[ni] = a_dst[gn];
        }
        int h0 = (n0 + wn) >> 5;          // wave's 2 heads: h0, h0+1
#pragma unroll
        for (int mi = 0; mi < 4; ++mi) {
#pragma unroll
            for (int r = 0; r < 4; ++r) {
                float s0 = acc[mi][0][r] * as_c[0] + acc[mi][1][r] * as_c[1];
                float s1 = acc[mi][2][r] * as_c[2] + acc[mi][3][r] * as_c[3];
                float d0 = acc[mi][0][r] * ad_c[0] + acc[mi][1][r] * ad_c[1];
                float d1 = acc[mi][2][r] * ad_c[2] + acc[mi][3][r] * ad_c[3];
#pragma unroll
                for (int off = 1; off < 16; off <<= 1) {
                    s0 += __shfl_xor(s0, off, 16);
                    s1 += __shfl_xor(s1, off, 16);
                    d0 += __shfl_xor(d0, off, 16);
                    d1 += __shfl_xor(d1, off, 16);
                }
                if (mrow == 0) {
                    int gm = m0 + wm + mi * 16 + quad * 4 + r;
                    if (gm < M) {
                        al_s[(size_t)h0 * N_NODES + gm]       = s0;
                        al_s[(size_t)(h0 + 1) * N_NODES + gm] = s1;
                        al_d[(size_t)h0 * N_NODES + gm]       = d0;
                        al_d[(size_t)(h0 + 1) * N_NODES + gm] = d1;
                    }
                }
            }
        }
    }
    if constexpr (LOGMODE == 2) {   // single head over 128 cols: cross-wave reduce
        __shared__ float s_red[4][2][128];
        float as_c[4], ad_c[4];
#pragma unroll
        for (int ni = 0; ni < 4; ++ni) {
            int gn = wn + ni * 16 + mrow;     // n0 == 0 (grid.x == 1)
            as_c[ni] = a_src[gn];
            ad_c[ni] = a_dst[gn];
        }
#pragma unroll
        for (int mi = 0; mi < 4; ++mi) {
#pragma unroll
            for (int r = 0; r < 4; ++r) {
                float s = acc[mi][0][r] * as_c[0] + acc[mi][1][r] * as_c[1]
                        + acc[mi][2][r] * as_c[2] + acc[mi][3][r] * as_c[3];
                float d = acc[mi][0][r] * ad_c[0] + acc[mi][1][r] * ad_c[1]
                        + acc[mi][2][r] * ad_c[2] + acc[mi][3][r] * ad_c[3];
#pragma unroll
                for (int off = 1; off < 16; off <<= 1) {
                    s += __shfl_xor(s, off, 16);
                    d += __shfl_xor(d, off, 16);
                }
                if (mrow == 0) {
                    int lrow = wm + mi * 16 + quad * 4 + r;
                    s_red[wave][0][lrow] = s;
                    s_red[wave][1][lrow] = d;
                }
            }
        }
        __syncthreads();
        if (t < 128) {
            int gm = m0 + t;
            if (gm < M) {
                int ws = t >> 6;
                al_s[gm] = s_red[ws][0][t] + s_red[ws + 2][0][t];
                al_d[gm] = s_red[ws][1][t] + s_red[ws + 2][1][t];
            }
        }
    }
}

// ---------------- W^T casts, one launch ----------------
__global__ void wtcast_all(const float* __restrict__ W1, const float* __restrict__ W2,
                           const float* __restrict__ W3, short* __restrict__ wt)
{
    int i = blockIdx.x * blockDim.x + threadIdx.x;
    if (i < 32768) {                       // W1: K=128, N=256
        int n = i / 128, k = i % 128;
        wt[i] = f2h(W1[(size_t)k * 256 + n]);
    } else if (i < 98304) {                // W2: K=256, N=256
        int j = i - 32768;
        int n = j / 256, k = j % 256;
        wt[i] = f2h(W2[(size_t)k * 256 + n]);
    } else if (i < 131072) {               // W3: K=256, N=128
        int j = i - 98304;
        int n = j / 256, k = j % 256;
        wt[i] = f2h(W3[(size_t)k * 128 + n]);
    }
}

// ---------------- CSR build ----------------
__global__ void deg_kernel(const int* __restrict__ ei, int* __restrict__ deg)
{
    int e = blockIdx.x * blockDim.x + threadIdx.x;
    if (e >= E_TOT) return;
    int d = (e < E_ORIG) ? ei[E_ORIG + e] : e - E_ORIG;
    atomicAdd(&deg[d], 1);
}

__global__ __launch_bounds__(256) void scan_p1(const int* __restrict__ deg, int* __restrict__ bsum)
{
    __shared__ int wsum[4];
    int t = threadIdx.x;
    int base = blockIdx.x * 1024 + t * 4;
    int s = 0;
    if (base + 3 < N_NODES) {
        int4 v = *(const int4*)(deg + base);
        s = v.x + v.y + v.z + v.w;
    } else if (base < N_NODES) {
        for (int j = 0; j < 4 && base + j < N_NODES; ++j) s += deg[base + j];
    }
#pragma unroll
    for (int d = 32; d; d >>= 1) s += __shfl_down(s, d);
    if ((t & 63) == 0) wsum[t >> 6] = s;
    __syncthreads();
    if (t == 0) bsum[blockIdx.x] = wsum[0] + wsum[1] + wsum[2] + wsum[3];
}

// p2 merged: each block redundantly prefixes the 49 block sums (cheap).
__global__ __launch_bounds__(256) void scan_p3(const int* __restrict__ deg,
                                               const int* __restrict__ bsum,
                                               int* __restrict__ row_ptr,
                                               int* __restrict__ cursor)
{
    __shared__ int tsum[256];
    int t = threadIdx.x;
    int b = blockIdx.x;
    int bpre = 0;
    for (int i = 0; i < b; ++i) bpre += bsum[i];
    int base = b * 1024 + t * 4;
    int d0 = 0, d1 = 0, d2 = 0, d3 = 0;
    if (base + 3 < N_NODES) {
        int4 v = *(const int4*)(deg + base);
        d0 = v.x; d1 = v.y; d2 = v.z; d3 = v.w;
    } else if (base < N_NODES) {
        d0 = deg[base];
        if (base + 1 < N_NODES) d1 = deg[base + 1];
        if (base + 2 < N_NODES) d2 = deg[base + 2];
    }
    int s = d0 + d1 + d2 + d3;
    tsum[t] = s;
    __syncthreads();
    for (int off = 1; off < 256; off <<= 1) {
        int u = (t >= off) ? tsum[t - off] : 0;
        __syncthreads();
        tsum[t] += u;
        __syncthreads();
    }
    int run = bpre + tsum[t] - s;
    if (base < N_NODES)     { row_ptr[base]     = run; cursor[base]     = run; run += d0; }
    if (base + 1 < N_NODES) { row_ptr[base + 1] = run; cursor[base + 1] = run; run += d1; }
    if (base + 2 < N_NODES) { row_ptr[base + 2] = run; cursor[base + 2] = run; run += d2; }
    if (base + 3 < N_NODES) { row_ptr[base + 3] = run; cursor[base + 3] = run; }
    if (b == SNB - 1 && t == 255) row_ptr[N_NODES] = bpre + tsum[255];
}

// packed CSR fill: colp = src | ((dst & 63) << 16). src < 65536; gather blocks are
// 64-aligned node ranges so dst - n0 == dst & 63.
__global__ void fill_kernel(const int* __restrict__ ei, int* __restrict__ cursor,
                            int* __restrict__ colp)
{
    int e = blockIdx.x * blockDim.x + threadIdx.x;
    if (e >= E_TOT) return;
    int s, d;
    if (e < E_ORIG) { s = ei[e]; d = ei[E_ORIG + e]; } else { s = d = e - E_ORIG; }
    int pos = atomicAdd(&cursor[d], 1);
    colp[pos] = s | ((d & 63) << 16);
}

// ---------------- slice-blocked gather, XCD-pinned, LDS-staged, straight 8-unroll ----------------
// R14's proven inner loop (named variables only - NO runtime-indexed arrays; R15's
// 2-deep pipeline spilled to scratch: WRITE_SIZE 25->762 MB, dur 94->270 us).
template<int HC, int H, bool BN, bool OUTH>
__global__ __launch_bounds__(256) void gat_gather_lds(const int* __restrict__ row_ptr,
                                                      const int* __restrict__ colp,
                                                      const short* __restrict__ ht,
                                                      const float* __restrict__ al_s,
                                                      const float* __restrict__ al_d,
                                                      const float* __restrict__ bias,
                                                      const float* __restrict__ gamma,
                                                      const float* __restrict__ beta,
                                                      const float* __restrict__ mean,
                                                      const float* __restrict__ var,
                                                      void* __restrict__ outp)
{
    constexpr int NBLK = HC / 32;
    __shared__ int2  s_cw[CAP];          // {src, half2(w*2^-8)}
    __shared__ float s_ald[64];          // al_d for the block's 64 dst nodes
    int blk  = blockIdx.x % NBLK;        // slice id == XCD id (mod 8)
    int nb   = blockIdx.x / NBLK;
    int t    = threadIdx.x;
    int n    = nb * 64 + (t >> 2);
    int lane = t & 3;
    int head = (blk * H) / NBLK;
    int c_loc = lane * 8;
    const short* hb  = ht + (size_t)blk * N_NODES * 32 + c_loc;
    const float* als = al_s + (size_t)head * N_NODES;

    int n0 = nb * 64;
    int n1 = n0 + 64; if (n1 > N_NODES) n1 = N_NODES;
    if (t < 64 && n0 + t < N_NODES) s_ald[t] = al_d[(size_t)head * N_NODES + n0 + t];
    int eb = row_ptr[n0], ee = row_ptr[n1];

    int mybeg = 0, myend = 0;
    if (n < N_NODES) { mybeg = row_ptr[n]; myend = row_ptr[n + 1]; }
    __syncthreads();

    __half2 acc0 = __float2half2_rn(0.f), acc1 = acc0, acc2 = acc0, acc3 = acc0;
    __half2 den2 = __float2half2_rn(0.f);
#define ACC(hv, w2) { \
        acc0 = __hfma2(w2, __builtin_bit_cast(__half2, hv.x), acc0); \
        acc1 = __hfma2(w2, __builtin_bit_cast(__half2, hv.y), acc1); \
        acc2 = __hfma2(w2, __builtin_bit_cast(__half2, hv.z), acc2); \
        acc3 = __hfma2(w2, __builtin_bit_cast(__half2, hv.w), acc3); }
#define STEP1(cw, hvar) \
        int4 hvar = *(const int4*)(hb + (size_t)(cw).x * 32);

    for (int w0 = eb; w0 < ee; w0 += CAP) {
        int w1 = w0 + CAP; if (w1 > ee) w1 = ee;
        // ---- cooperative staging (coalesced; one thread per edge) ----
        for (int i = w0 + t; i < w1; i += 256) {
            int cp = colp[i];
            int c = cp & 0xFFFF;
            float v = als[c] + s_ald[cp >> 16];
            v = v > 0.f ? v : 0.2f * v;
            __half2 w2 = __float2half2_rn(__expf(v) * WSCALE);
            s_cw[i - w0] = make_int2(c, __builtin_bit_cast(int, w2));
        }
        __syncthreads();
        // ---- per-node accumulate from LDS, straight 8-unroll ----
        int lo = mybeg > w0 ? mybeg : w0;
        int hi = myend < w1 ? myend : w1;
        int e = lo;
        for (; e + 7 < hi; e += 8) {
            int2 cw0 = s_cw[e - w0],     cw1 = s_cw[e - w0 + 1];
            int2 cw2 = s_cw[e - w0 + 2], cw3 = s_cw[e - w0 + 3];
            int2 cw4 = s_cw[e - w0 + 4], cw5 = s_cw[e - w0 + 5];
            int2 cw6 = s_cw[e - w0 + 6], cw7 = s_cw[e - w0 + 7];
            STEP1(cw0, h0) STEP1(cw1, h1) STEP1(cw2, h2) STEP1(cw3, h3)
            STEP1(cw4, h4) STEP1(cw5, h5) STEP1(cw6, h6) STEP1(cw7, h7)
            __half2 w20 = __builtin_bit_cast(__half2, cw0.y), w21 = __builtin_bit_cast(__half2, cw1.y);
            __half2 w22 = __builtin_bit_cast(__half2, cw2.y), w23 = __builtin_bit_cast(__half2, cw3.y);
            __half2 w24 = __builtin_bit_cast(__half2, cw4.y), w25 = __builtin_bit_cast(__half2, cw5.y);
            __half2 w26 = __builtin_bit_cast(__half2, cw6.y), w27 = __builtin_bit_cast(__half2, cw7.y);
            den2 = __hadd2(den2, __hadd2(__hadd2(w20, w21), __hadd2(w22, w23)));
            den2 = __hadd2(den2, __hadd2(__hadd2(w24, w25), __hadd2(w26, w27)));
            ACC(h0, w20); ACC(h1, w21); ACC(h2, w22); ACC(h3, w23);
            ACC(h4, w24); ACC(h5, w25); ACC(h6, w26); ACC(h7, w27);
        }
        for (; e + 3 < hi; e += 4) {
            int2 cw0 = s_cw[e - w0],     cw1 = s_cw[e - w0 + 1];
            int2 cw2 = s_cw[e - w0 + 2], cw3 = s_cw[e - w0 + 3];
            STEP1(cw0, h0) STEP1(cw1, h1) STEP1(cw2, h2) STEP1(cw3, h3)
            __half2 w20 = __builtin_bit_cast(__half2, cw0.y), w21 = __builtin_bit_cast(__half2, cw1.y);
            __half2 w22 = __builtin_bit_cast(__half2, cw2.y), w23 = __builtin_bit_cast(__half2, cw3.y);
            den2 = __hadd2(den2, __hadd2(__hadd2(w20, w21), __hadd2(w22, w23)));
            ACC(h0, w20); ACC(h1, w21); ACC(h2, w22); ACC(h3, w23);
        }
        for (; e < hi; ++e) {
            int2 cw = s_cw[e - w0];
            STEP1(cw, h0)
            __half2 w2 = __builtin_bit_cast(__half2, cw.y);
            den2 = __hadd2(den2, w2);
            ACC(h0, w2);
        }
        __syncthreads();
    }
#undef ACC
#undef STEP1
    if (n >= N_NODES) return;
    float inv = 1.0f / __low2float(den2);    // 2^-8 scale cancels (acc & den both carry it)
    float2 f0 = __half22float2(acc0), f1 = __half22float2(acc1);
    float2 f2 = __half22float2(acc2), f3 = __half22float2(acc3);
    float r[8] = { f0.x * inv, f0.y * inv, f1.x * inv, f1.y * inv,
                   f2.x * inv, f2.y * inv, f3.x * inv, f3.y * inv };
    int cb = blk * 32 + c_loc;
#pragma unroll
    for (int j = 0; j < 8; ++j) {
        int c = cb + j;
        float v = r[j] + bias[c];
        if (BN) {
            v = (v - mean[c]) * rsqrtf(var[c] + 1e-5f) * gamma[c] + beta[c];
            v = v > 0.f ? v : expm1f(v);   // ELU
        }
        r[j] = v;
    }
    if (OUTH) {
        short8 o;
#pragma unroll
        for (int j = 0; j < 8; ++j) o[j] = f2h(r[j]);
        *(short8*)((short*)outp + (size_t)n * HC + cb) = o;
    } else {
        float* op = (float*)outp + (size_t)n * HC + cb;
        *(float4*)op       = make_float4(r[0], r[1], r[2], r[3]);
        *(float4*)(op + 4) = make_float4(r[4], r[5], r[6], r[7]);
    }
}

extern "C" void kernel_launch(void* const* d_in, const int* in_sizes, int n_in,
                              void* d_out, int out_size, void* d_ws, size_t ws_size,
                              hipStream_t stream)
{
    const float* x   = (const float*)d_in[0];
    const int*   ei  = (const int*)d_in[1];
    const float* W1  = (const float*)d_in[2];
    const float* as1 = (const float*)d_in[3];
    const float* ad1 = (const float*)d_in[4];
    const float* b1  = (const float*)d_in[5];
    const float* g1  = (const float*)d_in[6];
    const float* be1 = (const float*)d_in[7];
    const float* mn1 = (const float*)d_in[8];
    const float* vr1 = (const float*)d_in[9];
    const float* W2  = (const float*)d_in[10];
    const float* as2 = (const float*)d_in[11];
    const float* ad2 = (const float*)d_in[12];
    const float* b2  = (const float*)d_in[13];
    const float* g2  = (const float*)d_in[14];
    const float* be2 = (const float*)d_in[15];
    const float* mn2 = (const float*)d_in[16];
    const float* vr2 = (const float*)d_in[17];
    const float* W3  = (const float*)d_in[18];
    const float* as3 = (const float*)d_in[19];
    const float* ad3 = (const float*)d_in[20];
    const float* b3  = (const float*)d_in[21];

    char* p = (char*)d_ws;
    short* hbuf    = (short*)p; p += (size_t)N_NODES * 256 * 2;     // 25.6 MB (slice-major h, fp16)
    short* obuf    = (short*)p; p += (size_t)N_NODES * 256 * 2;     // 25.6 MB (row-major layer out, fp16)
    short* wtbuf   = (short*)p; p += (size_t)131072 * 2;            // 256 KB (wt1|wt2|wt3)
    float* als     = (float*)p; p += (size_t)N_NODES * 8 * 4;       // head-major [h][n]
    float* ald     = (float*)p; p += (size_t)N_NODES * 8 * 4;
    int*   row_ptr = (int*)p;   p += (size_t)(N_NODES + 1) * 4;
    int*   colp    = (int*)p;   p += (size_t)E_TOT * 4;
    int*   deg     = (int*)p;   p += (size_t)N_NODES * 4;
    int*   cursor  = (int*)p;   p += (size_t)N_NODES * 4;
    int*   bsum    = (int*)p;   p += 64 * 4;

    short* wt1 = wtbuf;           // [256][128]
    short* wt2 = wtbuf + 32768;   // [256][256]
    short* wt3 = wtbuf + 98304;   // [128][256]

    float* out = (float*)d_out;

    // ----- CSR build + weight casts -----
    hipMemsetAsync(deg, 0, (size_t)N_NODES * 4, stream);
    deg_kernel<<<(E_TOT + 255) / 256, 256, 0, stream>>>(ei, deg);
    scan_p1<<<SNB, 256, 0, stream>>>(deg, bsum);
    scan_p3<<<SNB, 256, 0, stream>>>(deg, bsum, row_ptr, cursor);
    fill_kernel<<<(E_TOT + 255) / 256, 256, 0, stream>>>(ei, cursor, colp);
    wtcast_all<<<(131072 + 255) / 256, 256, 0, stream>>>(W1, W2, W3, wtbuf);

    // ----- layer 1: GAT(128 -> 8x32) + BN + ELU (x cast + logits fused into GEMM) -----
    gemm_f16<true, 1><<<dim3(2, (N_NODES + 127) / 128), 256, 0, stream>>>(
        x, wt1, hbuf, N_NODES, 256, 128, as1, ad1, als, ald);
    gat_gather_lds<256, 8, true, true><<<BPG * 8, 256, 0, stream>>>(
        row_ptr, colp, hbuf, als, ald, b1, g1, be1, mn1, vr1, obuf);

    // ----- layer 2: GAT(256 -> 8x32) + BN + ELU (logits fused into GEMM) -----
    gemm_f16<false, 1><<<dim3(2, (N_NODES + 127) / 128), 256, 0, stream>>>(
        obuf, wt2, hbuf, N_NODES, 256, 256, as2, ad2, als, ald);
    gat_gather_lds<256, 8, true, true><<<BPG * 8, 256, 0, stream>>>(
        row_ptr, colp, hbuf, als, ald, b2, g2, be2, mn2, vr2, obuf);

    // ----- layer 3: GAT(256 -> 1x128), heads=1 (logits fused via cross-wave reduce) -----
    gemm_f16<false, 2><<<dim3(1, (N_NODES + 127) / 128), 256, 0, stream>>>(
        obuf, wt3, hbuf, N_NODES, 128, 256, as3, ad3, als, ald);
    gat_gather_lds<128, 1, false, false><<<BPG * 4, 256, 0, stream>>>(
        row_ptr, colp, hbuf, als, ald, b3, nullptr, nullptr, nullptr, nullptr, out);
}